// Round 8
// baseline (298.277 us; speedup 1.0000x reference)
//
#include <hip/hip_runtime.h>
#include <math.h>

#define H 12
#define S 1024
#define D 128
#define NROWS (H * S) // 12288

typedef __attribute__((ext_vector_type(8))) _Float16 f16x8; // 8 fp16 in 4 VGPRs
typedef __attribute__((ext_vector_type(4))) float f32x4;
typedef __attribute__((ext_vector_type(4))) int i32x4;

__device__ __forceinline__ short f2h(float f) { // RNE float->fp16, bits as short
    _Float16 h = (_Float16)f;
    return __builtin_bit_cast(short, h);
}
__device__ __forceinline__ float h2f(short s) {
    return (float)__builtin_bit_cast(_Float16, s);
}
__device__ __forceinline__ f16x8 fneg8(f16x8 v) { // packed sign flip
    i32x4 u = __builtin_bit_cast(i32x4, v);
    u ^= (int)0x80008000;
    return __builtin_bit_cast(f16x8, u);
}

// ---- workspace layout (BYTE offsets) ----
// qp fp16 [12288][256] r/i ; kp fp16 [12288][128] r/i ; vpT fp16 [H][128][1024] r/i
// gp fp16 [12288][128] r/i ; acat fp16 [12288][256] r/i ; lam ;
// w16 fp16 per chunk-head 2*S*S ; stats float (exp-sum) per chunk-head 2*S
#define WS_QP_R   0ULL
#define WS_QP_I   6291456ULL
#define WS_KP_R   12582912ULL
#define WS_KP_I   15728640ULL
#define WS_VPT_R  18874368ULL
#define WS_VPT_I  22020096ULL
#define WS_GP_R   25165824ULL
#define WS_GP_I   28311552ULL
#define WS_ACAT_R 31457280ULL
#define WS_ACAT_I 37748736ULL
#define WS_LAM    44040192ULL
#define WS_SC     44040448ULL
#define W16_PER_HEAD   4194304ULL // 2*1024*1024*2B
#define STAT_PER_HEAD  8192ULL    // 2*1024*4B

// ============================================================
__global__ void lam_kernel(const float* __restrict__ lq1, const float* __restrict__ lk1,
                           const float* __restrict__ lq2, const float* __restrict__ lk2,
                           float* __restrict__ lam_out)
{
    int t = threadIdx.x; // 128 threads
    float p1 = lq1[t] * lk1[t];
    float p2 = lq2[t] * lk2[t];
    #pragma unroll
    for (int off = 32; off; off >>= 1) {
        p1 += __shfl_xor(p1, off);
        p2 += __shfl_xor(p2, off);
    }
    __shared__ float s1[2], s2[2];
    if ((t & 63) == 0) { s1[t >> 6] = p1; s2[t >> 6] = p2; }
    __syncthreads();
    if (t == 0) {
        float l1 = expf(s1[0] + s1[1]);
        float l2 = expf(s2[0] + s2[1]);
        float x = l1 - l2 + 0.3555090675909693f; // 0.8 - 0.6*exp(-0.3)
        lam_out[0] = 1.0f / (1.0f + expf(-x));
    }
}

// ============================================================
// ALL FOUR projections in ONE dispatch. grid = (192, 10), 64x64 tiles:
//  y 0-3: q-proj  (M=256, fp16 out, +pe_q)       col0 = y*64
//  y 4-5: k-proj  (M=128, fp16 out, +pe_k)       col0 = (y-4)*64
//  y 6-7: v-proj  (M=128, fp16 transposed out)   col0 = (y-6)*64
//  y 8-9: g-proj  (M=128, fp16 out)              col0 = (y-8)*64
// K-concat 256: out_r = [xr,xi].[wr,-wi]^T ; out_i = [xr,xi].[wi,wr]^T
// ============================================================
__global__ __launch_bounds__(256) void proj_all(
    const float* __restrict__ q_r, const float* __restrict__ q_i,
    const float* __restrict__ k_r, const float* __restrict__ k_i,
    const float* __restrict__ v_r, const float* __restrict__ v_i,
    const float* __restrict__ pe_q_r, const float* __restrict__ pe_q_i,
    const float* __restrict__ pe_k_r, const float* __restrict__ pe_k_i,
    const float* __restrict__ qw_r, const float* __restrict__ qw_i,
    const float* __restrict__ qb_r, const float* __restrict__ qb_i,
    const float* __restrict__ kw_r, const float* __restrict__ kw_i,
    const float* __restrict__ kb_r, const float* __restrict__ kb_i,
    const float* __restrict__ vw_r, const float* __restrict__ vw_i,
    const float* __restrict__ vb_r, const float* __restrict__ vb_i,
    const float* __restrict__ gw_r, const float* __restrict__ gw_i,
    const float* __restrict__ gb_r, const float* __restrict__ gb_i,
    short* __restrict__ qp_r, short* __restrict__ qp_i,
    short* __restrict__ kp_r, short* __restrict__ kp_i,
    short* __restrict__ vpT_r, short* __restrict__ vpT_i,
    short* __restrict__ gp_r, short* __restrict__ gp_i)
{
    const int y = blockIdx.y;
    const float *xr, *xi, *wr, *wi, *br, *bi, *per = nullptr, *pei = nullptr;
    short *outr_, *outi_;
    int M, omode, col0;
    if (y < 4)      { xr = q_r; xi = q_i; wr = qw_r; wi = qw_i; br = qb_r; bi = qb_i;
                      per = pe_q_r; pei = pe_q_i; outr_ = qp_r; outi_ = qp_i;
                      M = 256; omode = 1; col0 = y * 64; }
    else if (y < 6) { xr = k_r; xi = k_i; wr = kw_r; wi = kw_i; br = kb_r; bi = kb_i;
                      per = pe_k_r; pei = pe_k_i; outr_ = kp_r; outi_ = kp_i;
                      M = 128; omode = 1; col0 = (y - 4) * 64; }
    else if (y < 8) { xr = v_r; xi = v_i; wr = vw_r; wi = vw_i; br = vb_r; bi = vb_i;
                      outr_ = vpT_r; outi_ = vpT_i;
                      M = 128; omode = 2; col0 = (y - 6) * 64; }
    else            { xr = q_r; xi = q_i; wr = gw_r; wi = gw_i; br = gb_r; bi = gb_i;
                      outr_ = gp_r; outi_ = gp_i;
                      M = 128; omode = 1; col0 = (y - 8) * 64; }

    __shared__ short As[64 * 72], Brs[64 * 72], Bis[64 * 72];
    const int t = threadIdx.x;
    const int row0 = blockIdx.x * 64;
    const int lane = t & 63, wid = t >> 6;
    const int wm = (wid >> 1) * 32, wn = (wid & 1) * 32;
    const int fm = lane & 15, fq = lane >> 4;
    f32x4 zero4 = {0.f, 0.f, 0.f, 0.f};
    f32x4 accr[2][2], acci[2][2];
    #pragma unroll
    for (int i = 0; i < 2; ++i)
        #pragma unroll
        for (int j = 0; j < 2; ++j) { accr[i][j] = zero4; acci[i][j] = zero4; }

    for (int c = 0; c < 4; ++c) {
        const bool hi = (c >= 2);
        const int kb = (c & 1) * 64;
        const float* Asrc = hi ? xi : xr;
        const float* Brsrc = hi ? wi : wr;
        const float* Bisrc = hi ? wr : wi;
        const float bsign = hi ? -1.0f : 1.0f;
        __syncthreads();
        #pragma unroll
        for (int it = 0; it < 4; ++it) {
            int lin = it * 256 + t;
            int r = lin >> 4, k4 = (lin & 15) * 4;
            float4 va = *(const float4*)&Asrc[(size_t)(row0 + r) * 128 + kb + k4];
            *(short4*)&As[r * 72 + k4] = make_short4(f2h(va.x), f2h(va.y), f2h(va.z), f2h(va.w));
            float4 vr = *(const float4*)&Brsrc[(size_t)(col0 + r) * 128 + kb + k4];
            *(short4*)&Brs[r * 72 + k4] = make_short4(f2h(bsign * vr.x), f2h(bsign * vr.y),
                                                      f2h(bsign * vr.z), f2h(bsign * vr.w));
            float4 vi = *(const float4*)&Bisrc[(size_t)(col0 + r) * 128 + kb + k4];
            *(short4*)&Bis[r * 72 + k4] = make_short4(f2h(vi.x), f2h(vi.y), f2h(vi.z), f2h(vi.w));
        }
        __syncthreads();
        #pragma unroll
        for (int ks = 0; ks < 64; ks += 32) {
            f16x8 bfr[2], bfi[2];
            #pragma unroll
            for (int j = 0; j < 2; ++j) {
                bfr[j] = *(const f16x8*)&Brs[(wn + j * 16 + fm) * 72 + ks + fq * 8];
                bfi[j] = *(const f16x8*)&Bis[(wn + j * 16 + fm) * 72 + ks + fq * 8];
            }
            #pragma unroll
            for (int i = 0; i < 2; ++i) {
                f16x8 a = *(const f16x8*)&As[(wm + i * 16 + fm) * 72 + ks + fq * 8];
                #pragma unroll
                for (int j = 0; j < 2; ++j) {
                    accr[i][j] = __builtin_amdgcn_mfma_f32_16x16x32_f16(a, bfr[j], accr[i][j], 0, 0, 0);
                    acci[i][j] = __builtin_amdgcn_mfma_f32_16x16x32_f16(a, bfi[j], acci[i][j], 0, 0, 0);
                }
            }
        }
    }
    #pragma unroll
    for (int i = 0; i < 2; ++i)
        #pragma unroll
        for (int j = 0; j < 2; ++j) {
            int colc = col0 + wn + j * 16 + fm;
            float bbr = br[colc], bbi = bi[colc];
            if (omode == 2) {
                int rb = row0 + wm + i * 16 + fq * 4;
                int hq = rb >> 10, sq = rb & 1023;
                short4 o_r4 = make_short4(f2h(accr[i][j][0] + bbr), f2h(accr[i][j][1] + bbr),
                                          f2h(accr[i][j][2] + bbr), f2h(accr[i][j][3] + bbr));
                short4 o_i4 = make_short4(f2h(acci[i][j][0] + bbi), f2h(acci[i][j][1] + bbi),
                                          f2h(acci[i][j][2] + bbi), f2h(acci[i][j][3] + bbi));
                size_t ob = ((size_t)(hq * 128 + colc)) * 1024 + sq;
                *(short4*)&outr_[ob] = o_r4;
                *(short4*)&outi_[ob] = o_i4;
            } else {
                #pragma unroll
                for (int reg = 0; reg < 4; ++reg) {
                    int rr = row0 + wm + i * 16 + fq * 4 + reg;
                    float o_r = accr[i][j][reg] + bbr;
                    float o_i = acci[i][j][reg] + bbi;
                    if (per) {
                        o_r += per[(size_t)rr * 128 + (colc & 127)];
                        o_i += pei[(size_t)rr * 128 + (colc & 127)];
                    }
                    outr_[(size_t)rr * M + colc] = f2h(o_r);
                    outi_[(size_t)rr * M + colc] = f2h(o_i);
                }
            }
        }
}

// ============================================================
// o-projection: fp16 gated input gp, fp32 weights, fp32 out. 64x64 tiles.
// ============================================================
__global__ __launch_bounds__(256) void oproj_mfma(
    const short* __restrict__ gp_r, const short* __restrict__ gp_i,
    const float* __restrict__ wr, const float* __restrict__ wi,
    const float* __restrict__ br, const float* __restrict__ bi,
    float* __restrict__ outr, float* __restrict__ outi)
{
    __shared__ short As[64 * 72], Brs[64 * 72], Bis[64 * 72];
    const int t = threadIdx.x;
    const int row0 = blockIdx.x * 64, col0 = blockIdx.y * 64;
    const int lane = t & 63, wid = t >> 6;
    const int wm = (wid >> 1) * 32, wn = (wid & 1) * 32;
    const int fm = lane & 15, fq = lane >> 4;
    f32x4 zero4 = {0.f, 0.f, 0.f, 0.f};
    f32x4 accr[2][2], acci[2][2];
    #pragma unroll
    for (int i = 0; i < 2; ++i)
        #pragma unroll
        for (int j = 0; j < 2; ++j) { accr[i][j] = zero4; acci[i][j] = zero4; }

    for (int c = 0; c < 4; ++c) {
        const bool hi = (c >= 2);
        const int kb = (c & 1) * 64;
        const short* Asrc = hi ? gp_i : gp_r;
        const float* Brsrc = hi ? wi : wr;
        const float* Bisrc = hi ? wr : wi;
        const float bsign = hi ? -1.0f : 1.0f;
        __syncthreads();
        #pragma unroll
        for (int it = 0; it < 4; ++it) {
            int lin = it * 256 + t;
            int r = lin >> 4, k4 = (lin & 15) * 4;
            *(short4*)&As[r * 72 + k4] = *(const short4*)&Asrc[(size_t)(row0 + r) * 128 + kb + k4];
            float4 vr = *(const float4*)&Brsrc[(size_t)(col0 + r) * 128 + kb + k4];
            *(short4*)&Brs[r * 72 + k4] = make_short4(f2h(bsign * vr.x), f2h(bsign * vr.y),
                                                      f2h(bsign * vr.z), f2h(bsign * vr.w));
            float4 vi = *(const float4*)&Bisrc[(size_t)(col0 + r) * 128 + kb + k4];
            *(short4*)&Bis[r * 72 + k4] = make_short4(f2h(vi.x), f2h(vi.y), f2h(vi.z), f2h(vi.w));
        }
        __syncthreads();
        #pragma unroll
        for (int ks = 0; ks < 64; ks += 32) {
            f16x8 bfr[2], bfi[2];
            #pragma unroll
            for (int j = 0; j < 2; ++j) {
                bfr[j] = *(const f16x8*)&Brs[(wn + j * 16 + fm) * 72 + ks + fq * 8];
                bfi[j] = *(const f16x8*)&Bis[(wn + j * 16 + fm) * 72 + ks + fq * 8];
            }
            #pragma unroll
            for (int i = 0; i < 2; ++i) {
                f16x8 a = *(const f16x8*)&As[(wm + i * 16 + fm) * 72 + ks + fq * 8];
                #pragma unroll
                for (int j = 0; j < 2; ++j) {
                    accr[i][j] = __builtin_amdgcn_mfma_f32_16x16x32_f16(a, bfr[j], accr[i][j], 0, 0, 0);
                    acci[i][j] = __builtin_amdgcn_mfma_f32_16x16x32_f16(a, bfi[j], acci[i][j], 0, 0, 0);
                }
            }
        }
    }
    #pragma unroll
    for (int i = 0; i < 2; ++i)
        #pragma unroll
        for (int j = 0; j < 2; ++j) {
            int colc = col0 + wn + j * 16 + fm;
            float bbr = br[colc], bbi = bi[colc];
            #pragma unroll
            for (int reg = 0; reg < 4; ++reg) {
                int rr = row0 + wm + i * 16 + fq * 4 + reg;
                outr[(size_t)rr * 128 + colc] = accr[i][j][reg] + bbr;
                outi[(size_t)rr * 128 + colc] = acci[i][j][reg] + bbi;
            }
        }
}

// ============================================================
// Scores: one map per block, 64q x 128k tile, K-chunk 64 (proven config).
// phase1: sr += qr.kr ; si += qi.kr   phase2: sr += qi.ki ; si += (-qr).ki
// mag -> fp16 w16. NO max subtraction (mag <= ~45, exp fits fp32 easily):
// epilogue reduces exp(mag) over this block's 128 cols (shfl over fm lanes)
// and atomicAdds into stats[row] -> softmax denominator, no extra pass.
// ============================================================
__global__ __launch_bounds__(256) void score_mfma(
    const short* __restrict__ qp_r, const short* __restrict__ qp_i,
    const short* __restrict__ kp_r, const short* __restrict__ kp_i,
    short* __restrict__ w16, float* __restrict__ stats, int h0)
{
    __shared__ short Qr[64 * 72], Qi[64 * 72], Kt[128 * 72];
    const int t = threadIdx.x;
    const int hh = blockIdx.z >> 1, map = blockIdx.z & 1;
    const int h = h0 + hh;
    const int q0 = blockIdx.x * 64, c0 = blockIdx.y * 128;
    const int lane = t & 63, wid = t >> 6;
    const int wm = (wid >> 1) * 32, wn = (wid & 1) * 64;
    const int fm = lane & 15, fq = lane >> 4;
    f32x4 zero4 = {0.f, 0.f, 0.f, 0.f};
    f32x4 sr[2][4], si[2][4];
    #pragma unroll
    for (int i = 0; i < 2; ++i)
        #pragma unroll
        for (int j = 0; j < 4; ++j) { sr[i][j] = zero4; si[i][j] = zero4; }

    for (int kb = 0; kb < 2; ++kb) {
        const int kbase = map * 128 + kb * 64;
        __syncthreads();
        #pragma unroll
        for (int i = 0; i < 4; ++i) {
            int lin = i * 256 + t;
            int r = lin >> 4, k4 = (lin & 15) * 4;
            size_t qb = (size_t)(h * S + q0 + r) * 256 + kbase + k4;
            *(short4*)&Qr[r * 72 + k4] = *(const short4*)&qp_r[qb];
            *(short4*)&Qi[r * 72 + k4] = *(const short4*)&qp_i[qb];
        }
        #pragma unroll
        for (int i = 0; i < 8; ++i) {
            int lin = i * 256 + t;
            int r = lin >> 4, k4 = (lin & 15) * 4;
            *(short4*)&Kt[r * 72 + k4] =
                *(const short4*)&kp_r[(size_t)(h * S + c0 + r) * 128 + kb * 64 + k4];
        }
        __syncthreads();
        f16x8 aR[2][2], aI[2][2]; // [ks][i]
        #pragma unroll
        for (int ks = 0; ks < 2; ++ks)
            #pragma unroll
            for (int i = 0; i < 2; ++i) {
                int ao = (wm + i * 16 + fm) * 72 + ks * 32 + fq * 8;
                aR[ks][i] = *(const f16x8*)&Qr[ao];
                aI[ks][i] = *(const f16x8*)&Qi[ao];
            }
        #pragma unroll
        for (int ks = 0; ks < 2; ++ks) {
            f16x8 b[4];
            #pragma unroll
            for (int j = 0; j < 4; ++j)
                b[j] = *(const f16x8*)&Kt[(wn + j * 16 + fm) * 72 + ks * 32 + fq * 8];
            #pragma unroll
            for (int i = 0; i < 2; ++i)
                #pragma unroll
                for (int j = 0; j < 4; ++j) {
                    sr[i][j] = __builtin_amdgcn_mfma_f32_16x16x32_f16(aR[ks][i], b[j], sr[i][j], 0, 0, 0);
                    si[i][j] = __builtin_amdgcn_mfma_f32_16x16x32_f16(aI[ks][i], b[j], si[i][j], 0, 0, 0);
                }
        }
        __syncthreads();
        #pragma unroll
        for (int i = 0; i < 8; ++i) {
            int lin = i * 256 + t;
            int r = lin >> 4, k4 = (lin & 15) * 4;
            *(short4*)&Kt[r * 72 + k4] =
                *(const short4*)&kp_i[(size_t)(h * S + c0 + r) * 128 + kb * 64 + k4];
        }
        __syncthreads();
        #pragma unroll
        for (int ks = 0; ks < 2; ++ks) {
            f16x8 b[4];
            #pragma unroll
            for (int j = 0; j < 4; ++j)
                b[j] = *(const f16x8*)&Kt[(wn + j * 16 + fm) * 72 + ks * 32 + fq * 8];
            f16x8 nR0 = fneg8(aR[ks][0]), nR1 = fneg8(aR[ks][1]);
            #pragma unroll
            for (int j = 0; j < 4; ++j) {
                sr[0][j] = __builtin_amdgcn_mfma_f32_16x16x32_f16(aI[ks][0], b[j], sr[0][j], 0, 0, 0);
                si[0][j] = __builtin_amdgcn_mfma_f32_16x16x32_f16(nR0, b[j], si[0][j], 0, 0, 0);
                sr[1][j] = __builtin_amdgcn_mfma_f32_16x16x32_f16(aI[ks][1], b[j], sr[1][j], 0, 0, 0);
                si[1][j] = __builtin_amdgcn_mfma_f32_16x16x32_f16(nR1, b[j], si[1][j], 0, 0, 0);
            }
        }
    }
    const float scale = 0.08838834764831845f;
    float rsum[2][4] = {{0.f}};
    #pragma unroll
    for (int i = 0; i < 2; ++i)
        #pragma unroll
        for (int j = 0; j < 4; ++j) {
            int kcol = c0 + wn + j * 16 + fm;
            #pragma unroll
            for (int reg = 0; reg < 4; ++reg) {
                int q = q0 + wm + i * 16 + fq * 4 + reg;
                float r1 = sr[i][j][reg], I1 = si[i][j][reg];
                float m1 = sqrtf(fmaf(r1, r1, fmaf(I1, I1, 1e-8f))) * scale;
                short mh = f2h(m1);
                w16[(((size_t)hh * 2 + map) * S + q) * S + kcol] = mh;
                rsum[i][reg] += __expf(h2f(mh)); // sum from the SAME rounded value av reads
            }
        }
    // reduce over the 16 fm lanes (cols), then one atomicAdd per row per wave
    float* srow = stats + ((size_t)hh * 2 + map) * S;
    #pragma unroll
    for (int i = 0; i < 2; ++i)
        #pragma unroll
        for (int reg = 0; reg < 4; ++reg) {
            float v = rsum[i][reg];
            v += __shfl_xor(v, 1);
            v += __shfl_xor(v, 2);
            v += __shfl_xor(v, 4);
            v += __shfl_xor(v, 8);
            if (fm == 0)
                atomicAdd(&srow[q0 + wm + i * 16 + fq * 4 + reg], v);
        }
}

// ============================================================
// AV: 32q x full 128d, both maps, ONE complex comp per block (blockIdx.y).
// W tiles = exp(mag)*inv_sum computed at staging (no max). V from vpT[h][d][s].
// acat out fp16.
// ============================================================
__global__ __launch_bounds__(256) void av_mfma(
    const short* __restrict__ w16, const float* __restrict__ stats,
    const short* __restrict__ vpT_r, const short* __restrict__ vpT_i,
    short* __restrict__ acat_r, short* __restrict__ acat_i, int h0)
{
    __shared__ short W1[32 * 72], W2[32 * 72], Vc[128 * 72];
    const int t = threadIdx.x;
    const int hh = blockIdx.z, h = h0 + hh;
    const int comp = blockIdx.y;
    const int q0 = blockIdx.x * 32;
    const short* vpT = comp ? vpT_i : vpT_r;
    short* acat = comp ? acat_i : acat_r;
    const float* st1 = stats + ((size_t)hh * 2 + 0) * S;
    const float* st2 = stats + ((size_t)hh * 2 + 1) * S;
    const int lane = t & 63, wid = t >> 6;
    const int wm = (wid >> 1) * 16, wn = (wid & 1) * 64;
    const int fm = lane & 15, fq = lane >> 4;
    f32x4 zero4 = {0.f, 0.f, 0.f, 0.f};
    f32x4 a1[4], a2[4];
    #pragma unroll
    for (int j = 0; j < 4; ++j) { a1[j] = zero4; a2[j] = zero4; }

    for (int k0 = 0; k0 < S; k0 += 64) {
        __syncthreads();
        #pragma unroll
        for (int it = 0; it < 2; ++it) {
            int lin = it * 256 + t;
            int r = lin >> 4, k4 = (lin & 15) * 4;
            float inv1 = 1.0f / st1[q0 + r];
            float inv2 = 1.0f / st2[q0 + r];
            short4 m1 = *(const short4*)&w16[(((size_t)hh * 2 + 0) * S + q0 + r) * S + k0 + k4];
            short4 m2 = *(const short4*)&w16[(((size_t)hh * 2 + 1) * S + q0 + r) * S + k0 + k4];
            *(short4*)&W1[r * 72 + k4] = make_short4(
                f2h(__expf(h2f(m1.x)) * inv1), f2h(__expf(h2f(m1.y)) * inv1),
                f2h(__expf(h2f(m1.z)) * inv1), f2h(__expf(h2f(m1.w)) * inv1));
            *(short4*)&W2[r * 72 + k4] = make_short4(
                f2h(__expf(h2f(m2.x)) * inv2), f2h(__expf(h2f(m2.y)) * inv2),
                f2h(__expf(h2f(m2.z)) * inv2), f2h(__expf(h2f(m2.w)) * inv2));
        }
        #pragma unroll
        for (int it = 0; it < 8; ++it) {
            int lin = it * 256 + t;
            int dd = lin >> 4, k4 = (lin & 15) * 4;
            *(short4*)&Vc[dd * 72 + k4] = *(const short4*)&vpT[(size_t)(h * 128 + dd) * 1024 + k0 + k4];
        }
        __syncthreads();
        #pragma unroll
        for (int ks = 0; ks < 64; ks += 32) {
            f16x8 b[4];
            #pragma unroll
            for (int j = 0; j < 4; ++j)
                b[j] = *(const f16x8*)&Vc[(wn + j * 16 + fm) * 72 + ks + fq * 8];
            int wo = (wm + fm) * 72 + ks + fq * 8;
            f16x8 w1f = *(const f16x8*)&W1[wo];
            f16x8 w2f = *(const f16x8*)&W2[wo];
            #pragma unroll
            for (int j = 0; j < 4; ++j) {
                a1[j] = __builtin_amdgcn_mfma_f32_16x16x32_f16(w1f, b[j], a1[j], 0, 0, 0);
                a2[j] = __builtin_amdgcn_mfma_f32_16x16x32_f16(w2f, b[j], a2[j], 0, 0, 0);
            }
        }
    }
    #pragma unroll
    for (int j = 0; j < 4; ++j) {
        int d = wn + j * 16 + fm;
        #pragma unroll
        for (int reg = 0; reg < 4; ++reg) {
            int q = q0 + wm + fq * 4 + reg;
            size_t rowb = (size_t)(h * S + q) * 256;
            acat[rowb + d]       = f2h(a1[j][reg]);
            acat[rowb + 128 + d] = f2h(a2[j][reg]);
        }
    }
}

// ============================================================
// RMS over 256 complex + sub_w + (a1 - lam*a2) + complex gate.
// acat fp16 in, gp fp16 in/out (in place).
// ============================================================
__global__ __launch_bounds__(256) void rmsgate_kernel(
    const short* __restrict__ acat_r, const short* __restrict__ acat_i,
    const float* __restrict__ sub_w, const float* __restrict__ lam_ptr,
    short* __restrict__ gp_r, short* __restrict__ gp_i)
{
    int row = blockIdx.x;
    int t = threadIdx.x;
    float ar = h2f(acat_r[(size_t)row * 256 + t]);
    float ai = h2f(acat_i[(size_t)row * 256 + t]);
    float ss = fmaf(ar, ar, ai * ai);
    #pragma unroll
    for (int off = 32; off; off >>= 1) ss += __shfl_xor(ss, off);
    __shared__ float red[4];
    if ((t & 63) == 0) red[t >> 6] = ss;
    __syncthreads();
    float total = red[0] + red[1] + red[2] + red[3];
    float inv_rms = 1.0f / sqrtf(total * (1.0f / 256.0f) + 1e-5f);
    float sw = sub_w[t];
    __shared__ float Cr[256], Ci[256];
    Cr[t] = ar * inv_rms * sw;
    Ci[t] = ai * inv_rms * sw;
    __syncthreads();
    if (t < 128) {
        float lam = lam_ptr[0];
        float o_r = Cr[t] - lam * Cr[t + 128];
        float o_i = Ci[t] - lam * Ci[t + 128];
        float gr = h2f(gp_r[(size_t)row * 128 + t]);
        float gi = h2f(gp_i[(size_t)row * 128 + t]);
        gp_r[(size_t)row * 128 + t] = f2h(gr * o_r - gi * o_i);
        gp_i[(size_t)row * 128 + t] = f2h(gr * o_i + gi * o_r);
    }
}

// ============================================================
extern "C" void kernel_launch(void* const* d_in, const int* in_sizes, int n_in,
                              void* d_out, int out_size, void* d_ws, size_t ws_size,
                              hipStream_t stream)
{
    (void)in_sizes; (void)n_in; (void)out_size;
    const float* q_r    = (const float*)d_in[0];
    const float* q_i    = (const float*)d_in[1];
    const float* k_r    = (const float*)d_in[2];
    const float* k_i    = (const float*)d_in[3];
    const float* v_r    = (const float*)d_in[4];
    const float* v_i    = (const float*)d_in[5];
    const float* pe_q_r = (const float*)d_in[6];
    const float* pe_q_i = (const float*)d_in[7];
    const float* pe_k_r = (const float*)d_in[8];
    const float* pe_k_i = (const float*)d_in[9];
    const float* qw_r   = (const float*)d_in[10];
    const float* qw_i   = (const float*)d_in[11];
    const float* qb_r   = (const float*)d_in[12];
    const float* qb_i   = (const float*)d_in[13];
    const float* kw_r   = (const float*)d_in[14];
    const float* kw_i   = (const float*)d_in[15];
    const float* kb_r   = (const float*)d_in[16];
    const float* kb_i   = (const float*)d_in[17];
    const float* vw_r   = (const float*)d_in[18];
    const float* vw_i   = (const float*)d_in[19];
    const float* vb_r   = (const float*)d_in[20];
    const float* vb_i   = (const float*)d_in[21];
    const float* gw_r   = (const float*)d_in[22];
    const float* gw_i   = (const float*)d_in[23];
    const float* gb_r   = (const float*)d_in[24];
    const float* gb_i   = (const float*)d_in[25];
    const float* ow_r   = (const float*)d_in[26];
    const float* ow_i   = (const float*)d_in[27];
    const float* ob_r   = (const float*)d_in[28];
    const float* ob_i   = (const float*)d_in[29];
    const float* lq1    = (const float*)d_in[30];
    const float* lk1    = (const float*)d_in[31];
    const float* lq2    = (const float*)d_in[32];
    const float* lk2    = (const float*)d_in[33];
    const float* sub_w  = (const float*)d_in[34];

    char* ws = (char*)d_ws;
    short* qp_r   = (short*)(ws + WS_QP_R);
    short* qp_i   = (short*)(ws + WS_QP_I);
    short* kp_r   = (short*)(ws + WS_KP_R);
    short* kp_i   = (short*)(ws + WS_KP_I);
    short* vpT_r  = (short*)(ws + WS_VPT_R);
    short* vpT_i  = (short*)(ws + WS_VPT_I);
    short* gp_r   = (short*)(ws + WS_GP_R);
    short* gp_i   = (short*)(ws + WS_GP_I);
    short* acat_r = (short*)(ws + WS_ACAT_R);
    short* acat_i = (short*)(ws + WS_ACAT_I);
    float* lam    = (float*)(ws + WS_LAM);
    short* w16    = (short*)(ws + WS_SC);

    float* out_r = (float*)d_out;
    float* out_i = out_r + (size_t)NROWS * D;

    // head-chunking by workspace (depends only on ws_size -> graph-safe)
    size_t avail = ws_size > WS_SC ? ws_size - WS_SC : 0;
    int nh_chunk = (int)(avail / (W16_PER_HEAD + STAT_PER_HEAD));
    if (nh_chunk < 1) nh_chunk = 1;
    if (nh_chunk > H) nh_chunk = H;
    float* stats = (float*)(ws + WS_SC + (size_t)nh_chunk * W16_PER_HEAD);

    lam_kernel<<<1, 128, 0, stream>>>(lq1, lk1, lq2, lk2, lam);

    // ALL projections in one dispatch (q/k -> fp16 +PE; v -> fp16 T; g -> fp16)
    proj_all<<<dim3(192, 10), 256, 0, stream>>>(
        q_r, q_i, k_r, k_i, v_r, v_i, pe_q_r, pe_q_i, pe_k_r, pe_k_i,
        qw_r, qw_i, qb_r, qb_i, kw_r, kw_i, kb_r, kb_i,
        vw_r, vw_i, vb_r, vb_i, gw_r, gw_i, gb_r, gb_i,
        qp_r, qp_i, kp_r, kp_i, vpT_r, vpT_i, gp_r, gp_i);

    for (int h0 = 0; h0 < H; h0 += nh_chunk) {
        int nhh = (H - h0 < nh_chunk) ? (H - h0) : nh_chunk;
        hipMemsetAsync(stats, 0, (size_t)nhh * 2 * S * sizeof(float), stream);
        score_mfma<<<dim3(16, 8, nhh * 2), 256, 0, stream>>>(qp_r, qp_i, kp_r, kp_i, w16, stats, h0);
        av_mfma<<<dim3(32, 2, nhh), 256, 0, stream>>>(w16, stats, vpT_r, vpT_i, acat_r, acat_i, h0);
    }

    rmsgate_kernel<<<NROWS, 256, 0, stream>>>(acat_r, acat_i, sub_w, lam, gp_r, gp_i);

    oproj_mfma<<<dim3(192, 2), 256, 0, stream>>>(gp_r, gp_i, ow_r, ow_i, ob_r, ob_i, out_r, out_i);
}